// Round 14
// baseline (380.599 us; speedup 1.0000x reference)
//
#include <hip/hip_runtime.h>

typedef short bf16x8 __attribute__((ext_vector_type(8)));
typedef float f32x16 __attribute__((ext_vector_type(16)));

#define GLOAD_LDS16(g, l) __builtin_amdgcn_global_load_lds(                    \
    (const __attribute__((address_space(1))) unsigned int*)(g),                \
    (__attribute__((address_space(3))) unsigned int*)(l), 16, 0, 0)

// round-to-nearest-even fp32 -> bf16 (bits)
static __device__ __forceinline__ unsigned short f2bf(float x) {
    unsigned u = __builtin_bit_cast(unsigned, x);
    unsigned r = (u + 0x7FFFu + ((u >> 16) & 1u)) >> 16;
    return (unsigned short)r;
}
static __device__ __forceinline__ float bf2f(unsigned short h) {
    unsigned u = (unsigned)h << 16;
    return __builtin_bit_cast(float, u);
}

// Workspace (shorts): A1[P*16] | A2[P*16] | B1[P*16] | B2[P*16]

// Kernel 1: per point p build MFMA K-vectors (bf16, hi/lo split) for two grams:
//   gram1: denom = 1 + s_i + s_j - 2<c_i,c_j>;  gram2: dot = <n_i,n_j>
// 32x32x16 fragment layout (verified R5-R13, absmax 0.0): point p -> tile=p>>5,
// m=p&31; k0..7 chunk -> lane m, k8..15 -> lane 32+m.
// Targets carry NEGATED normals (folds e_ss - 2 e_st + e_tt into one sum).
__global__ void dc_pack(const float* __restrict__ verts,
                        const float* __restrict__ tnorm,
                        const float* __restrict__ tcent,
                        const int* __restrict__ idx,
                        unsigned short* __restrict__ ws,
                        float* __restrict__ out,
                        int N, int M) {
    int p = blockIdx.x * blockDim.x + threadIdx.x;
    if (p == 0) out[0] = 0.0f;
    int P = N + M;
    if (p >= P) return;

    float cx, cy, cz, nx, ny, nz;
    if (p < N) {
        int i0 = idx[3 * p + 0], i1 = idx[3 * p + 1], i2 = idx[3 * p + 2];
        float ax = verts[3 * i0], ay = verts[3 * i0 + 1], az = verts[3 * i0 + 2];
        float bx = verts[3 * i1], by = verts[3 * i1 + 1], bz = verts[3 * i1 + 2];
        float qx = verts[3 * i2], qy = verts[3 * i2 + 1], qz = verts[3 * i2 + 2];
        float ux = ax - bx, uy = ay - by, uz = az - bz;
        float vx = qx - bx, vy = qy - by, vz = qz - bz;
        nx = 0.5f * (uy * vz - uz * vy);
        ny = 0.5f * (uz * vx - ux * vz);
        nz = 0.5f * (ux * vy - uy * vx);
        cx = (ax + bx + qx) * (1.0f / 3.0f);
        cy = (ay + by + qy) * (1.0f / 3.0f);
        cz = (az + bz + qz) * (1.0f / 3.0f);
    } else {
        int t = p - N;
        cx = tcent[3 * t]; cy = tcent[3 * t + 1]; cz = tcent[3 * t + 2];
        nx = -tnorm[3 * t]; ny = -tnorm[3 * t + 1]; nz = -tnorm[3 * t + 2];
    }

    unsigned short chx = f2bf(cx), chy = f2bf(cy), chz = f2bf(cz);
    unsigned short clx = f2bf(cx - bf2f(chx));
    unsigned short cly = f2bf(cy - bf2f(chy));
    unsigned short clz = f2bf(cz - bf2f(chz));
    unsigned short nhx = f2bf(nx), nhy = f2bf(ny), nhz = f2bf(nz);
    unsigned short nlx = f2bf(nx - bf2f(nhx));
    unsigned short nly = f2bf(ny - bf2f(nhy));
    unsigned short nlz = f2bf(nz - bf2f(nhz));
    float ex = bf2f(chx) + bf2f(clx);
    float ey = bf2f(chy) + bf2f(cly);
    float ez = bf2f(chz) + bf2f(clz);
    float s = ex * ex + ey * ey + ez * ez;
    unsigned short sh = f2bf(s), sl = f2bf(s - bf2f(sh));
    unsigned short m2hx = f2bf(-2.0f * bf2f(chx)), m2hy = f2bf(-2.0f * bf2f(chy)), m2hz = f2bf(-2.0f * bf2f(chz));
    unsigned short m2lx = f2bf(-2.0f * bf2f(clx)), m2ly = f2bf(-2.0f * bf2f(cly)), m2lz = f2bf(-2.0f * bf2f(clz));
    const unsigned short one = 0x3F80;

    __align__(16) unsigned short A1v[16] = {
        m2hx, m2hy, m2hz,  m2hx, m2hy, m2hz,  m2lx, m2ly, m2lz,
        sh, sl,  one, one,  one,  0, 0 };
    __align__(16) unsigned short B1v[16] = {
        chx, chy, chz,  clx, cly, clz,  chx, chy, chz,
        one, one,  sh, sl,  one,  0, 0 };
    __align__(16) unsigned short A2v[16] = {
        nhx, nhy, nhz,  nhx, nhy, nhz,  nlx, nly, nlz,
        0, 0, 0, 0, 0, 0, 0 };
    __align__(16) unsigned short B2v[16] = {
        nhx, nhy, nhz,  nlx, nly, nlz,  nhx, nhy, nhz,
        0, 0, 0, 0, 0, 0, 0 };

    size_t arr = (size_t)P * 16;
    unsigned short* A1 = ws;
    unsigned short* A2 = ws + arr;
    unsigned short* B1 = ws + 2 * arr;
    unsigned short* B2 = ws + 3 * arr;

    int tile = p >> 5, m = p & 31;
    size_t lo = ((size_t)tile * 64 + m) * 8;       // k0..7 -> lane m
    size_t hi = lo + 32 * 8;                       // k8..15 -> lane 32+m

    *(uint4*)(A1 + lo) = *(const uint4*)&A1v[0];
    *(uint4*)(A1 + hi) = *(const uint4*)&A1v[8];
    *(uint4*)(A2 + lo) = *(const uint4*)&A2v[0];
    *(uint4*)(A2 + hi) = *(const uint4*)&A2v[8];
    *(uint4*)(B1 + lo) = *(const uint4*)&B1v[0];
    *(uint4*)(B1 + hi) = *(const uint4*)&B1v[8];
    *(uint4*)(B2 + lo) = *(const uint4*)&B2v[0];
    *(uint4*)(B2 + hi) = *(const uint4*)&B2v[8];
}

// 4-way batched reciprocal: sum of 4 x/a terms via 1 rcp (trans-pipe 4x cut).
static __device__ __forceinline__ void acc4(float4& part, const f32x16& d1, const f32x16& d2) {
#pragma unroll
    for (int g = 0; g < 4; ++g) {
        const int r = 4 * g;
        float p01 = d1[r] * d1[r + 1];
        float p23 = d1[r + 2] * d1[r + 3];
        float n01 = fmaf(d2[r], d1[r + 1], d2[r + 1] * d1[r]);
        float n23 = fmaf(d2[r + 2], d1[r + 3], d2[r + 3] * d1[r + 2]);
        float t   = p01 * p23;
        float num = fmaf(n01, p23, n23 * p01);
        (&part.x)[g] = fmaf(num, __builtin_amdgcn_rcpf(t), (&part.x)[g]);
    }
}

// Kernel 2: row-paired circular sweep, WAVE-PRIVATE async LDS staging,
// ZERO barriers in the hot path.
// Rows (I0=2rp, I1=I0+1) share j-window W=[I0+1, I0+256] (mod nT):
//   contrib(rp) = 2*sum_W [T(I0,j)+T(I1,j)]
//               + T(I0,I0) + T(I1,I0+257) - T(I0,I0+256) - T(I1,I0+1)
// Diagnosis R9-R13: effective L2 latency under load (~2000+ cyc) was paid
// once PER ITERATION -- register prefetch is depth-1 (R9/R10) and the LDS
// double-buffer's __syncthreads drains the just-issued prefetch (R12, the
// m97 barrier-drain trap). Here each wave owns 4 tiles: fire all 8
// global_load_lds up front (no dest registers), ONE s_waitcnt, then consume
// from LDS. Latency paid once per wave. 256 rp x 64 chunks = 16384 waves =
// 4096 blocks; LDS 32 KB/block -> 4 blocks/CU -> 4 uniform batches.
__global__ __launch_bounds__(256, 4) void dc_pair_mfma(
    const unsigned short* __restrict__ ws, float* __restrict__ out, int P) {
    __shared__ unsigned short sB[4][4][1024];  // [wave][slot][b1(512)|b2(512)] shorts
    __shared__ float wsum[4];

    const int nT = P >> 5;                     // 512
    size_t arr = (size_t)P * 16;
    const unsigned short* A1 = ws;
    const unsigned short* A2 = ws + arr;
    const unsigned short* B1 = ws + 2 * arr;
    const unsigned short* B2 = ws + 3 * arr;

    int tid = threadIdx.x;
    int lane = tid & 63, wv = tid >> 6;
    int gi = blockIdx.x * 4 + wv;              // 0..16383
    int rp = gi >> 6, c = gi & 63;             // row-pair, 4-tile chunk
    int I0 = 2 * rp, I1 = I0 + 1;

    const size_t lo = (size_t)lane * 8;        // shorts: lane's 16B frag chunk

    // ---- stage this wave's 4 tiles (8 async global->LDS, fire-and-forget)
#pragma unroll
    for (int t = 0; t < 4; ++t) {
        int j = I0 + 1 + 4 * c + t;            // window offset d = 4c+1+t
        if (j >= nT) j -= nT;
        const unsigned short* g1 = B1 + (size_t)j * 512 + lo;
        const unsigned short* g2 = B2 + (size_t)j * 512 + lo;
        GLOAD_LDS16(g1, &sB[wv][t][0]);        // HW: base + lane*16
        GLOAD_LDS16(g2, &sB[wv][t][512]);
    }

    // A fragments (regular loads; compiler-managed vmcnt)
    bf16x8 a1_0 = *(const bf16x8*)(A1 + (size_t)I0 * 512 + lo);
    bf16x8 a2_0 = *(const bf16x8*)(A2 + (size_t)I0 * 512 + lo);
    bf16x8 a1_1 = *(const bf16x8*)(A1 + (size_t)I1 * 512 + lo);
    bf16x8 a2_1 = *(const bf16x8*)(A2 + (size_t)I1 * 512 + lo);

    const f32x16 zero = {0.f,0.f,0.f,0.f,0.f,0.f,0.f,0.f,0.f,0.f,0.f,0.f,0.f,0.f,0.f,0.f};
    float4 partA = make_float4(0.f, 0.f, 0.f, 0.f);
    float4 corrP = make_float4(0.f, 0.f, 0.f, 0.f);
    float4 corrM = make_float4(0.f, 0.f, 0.f, 0.f);

    __builtin_amdgcn_s_waitcnt(0);             // ONE drain: all staging done
    // (wave-private region: no __syncthreads needed, no prefetch to drain)

    // ---- consume 4 tiles from LDS
#pragma unroll
    for (int t = 0; t < 4; ++t) {
        const bf16x8 b1 = *(const bf16x8*)&sB[wv][t][lane * 8];
        const bf16x8 b2 = *(const bf16x8*)&sB[wv][t][512 + lane * 8];
        f32x16 d1 = __builtin_amdgcn_mfma_f32_32x32x16_bf16(a1_0, b1, zero, 0, 0, 0);
        f32x16 d2 = __builtin_amdgcn_mfma_f32_32x32x16_bf16(a2_0, b2, zero, 0, 0, 0);
        acc4(partA, d1, d2);
        f32x16 e1 = __builtin_amdgcn_mfma_f32_32x32x16_bf16(a1_1, b1, zero, 0, 0, 0);
        f32x16 e2 = __builtin_amdgcn_mfma_f32_32x32x16_bf16(a2_1, b2, zero, 0, 0, 0);
        acc4(partA, e1, e2);
    }

    // ---- corrections (rare waves; direct global loads)
    auto one_tile = [&](float4& part, const bf16x8& x1, const bf16x8& x2, int jm) {
        const bf16x8 b1 = *(const bf16x8*)(B1 + (size_t)jm * 512 + lo);
        const bf16x8 b2 = *(const bf16x8*)(B2 + (size_t)jm * 512 + lo);
        f32x16 d1 = __builtin_amdgcn_mfma_f32_32x32x16_bf16(x1, b1, zero, 0, 0, 0);
        f32x16 d2 = __builtin_amdgcn_mfma_f32_32x32x16_bf16(x2, b2, zero, 0, 0, 0);
        acc4(part, d1, d2);
    };
    if (c == 0) {
        one_tile(corrP, a1_0, a2_0, I0);                // +T(I0,I0)
        one_tile(corrM, a1_1, a2_1, I0 + 1);            // -T(I1,I0+1)
    } else if (c == 63) {
        int v = I0 + 256; if (v >= nT) v -= nT;
        int y = I0 + 257; if (y >= nT) y -= nT;
        one_tile(corrM, a1_0, a2_0, v);                 // -T(I0,I0+256)
        one_tile(corrP, a1_1, a2_1, y);                 // +T(I1,I0+257)
    }

    float s = 2.0f * (partA.x + partA.y + partA.z + partA.w)
            + (corrP.x + corrP.y + corrP.z + corrP.w)
            - (corrM.x + corrM.y + corrM.z + corrM.w);
#pragma unroll
    for (int off = 32; off > 0; off >>= 1) s += __shfl_down(s, off, 64);
    if (lane == 0) wsum[wv] = s;
    __syncthreads();                           // epilogue only
    if (tid == 0) {
        float t = wsum[0] + wsum[1] + wsum[2] + wsum[3];
        atomicAdd(out, t);
    }
}

extern "C" void kernel_launch(void* const* d_in, const int* in_sizes, int n_in,
                              void* d_out, int out_size, void* d_ws, size_t ws_size,
                              hipStream_t stream) {
    const float* verts = (const float*)d_in[0];   // (V,3) f32
    const float* tnorm = (const float*)d_in[1];   // (M,3) f32
    const float* tcent = (const float*)d_in[2];   // (M,3) f32
    const int*   sidx  = (const int*)d_in[3];     // (N,3) i32

    int M = in_sizes[1] / 3;
    int N = in_sizes[3] / 3;
    int P = N + M;                                // 16384

    unsigned short* ws = (unsigned short*)d_ws;   // A1|A2|B1|B2 = 4 MB
    float* out = (float*)d_out;

    int bblocks = (P + 255) / 256;
    dc_pack<<<bblocks, 256, 0, stream>>>(verts, tnorm, tcent, sidx, ws, out, N, M);

    // 256 rp x 64 chunks = 16384 waves = 4096 blocks (4/CU, 4 uniform batches)
    dc_pair_mfma<<<4096, 256, 0, stream>>>(ws, out, P);
}

// Round 15
// 118.754 us; speedup vs baseline: 3.2049x; 3.2049x over previous
//
#include <hip/hip_runtime.h>

typedef short bf16x8 __attribute__((ext_vector_type(8)));
typedef float f32x16 __attribute__((ext_vector_type(16)));

#define GLOAD_LDS16(g, l) __builtin_amdgcn_global_load_lds(                    \
    (const __attribute__((address_space(1))) unsigned int*)(g),                \
    (__attribute__((address_space(3))) unsigned int*)(l), 16, 0, 0)

// round-to-nearest-even fp32 -> bf16 (bits)
static __device__ __forceinline__ unsigned short f2bf(float x) {
    unsigned u = __builtin_bit_cast(unsigned, x);
    unsigned r = (u + 0x7FFFu + ((u >> 16) & 1u)) >> 16;
    return (unsigned short)r;
}
static __device__ __forceinline__ float bf2f(unsigned short h) {
    unsigned u = (unsigned)h << 16;
    return __builtin_bit_cast(float, u);
}

// Workspace (shorts): A1[P*16] | A2[P*16] | B1[P*16] | B2[P*16]

// Kernel 1: per point p build MFMA K-vectors (bf16, hi/lo split) for two grams:
//   gram1: denom = 1 + s_i + s_j - 2<c_i,c_j>;  gram2: dot = <n_i,n_j>
// 32x32x16 fragment layout (verified R5-R14, absmax 0.0): point p -> tile=p>>5,
// m=p&31; k0..7 chunk -> lane m, k8..15 -> lane 32+m.
// Targets carry NEGATED normals (folds e_ss - 2 e_st + e_tt into one sum).
__global__ void dc_pack(const float* __restrict__ verts,
                        const float* __restrict__ tnorm,
                        const float* __restrict__ tcent,
                        const int* __restrict__ idx,
                        unsigned short* __restrict__ ws,
                        float* __restrict__ out,
                        int N, int M) {
    int p = blockIdx.x * blockDim.x + threadIdx.x;
    if (p == 0) out[0] = 0.0f;
    int P = N + M;
    if (p >= P) return;

    float cx, cy, cz, nx, ny, nz;
    if (p < N) {
        int i0 = idx[3 * p + 0], i1 = idx[3 * p + 1], i2 = idx[3 * p + 2];
        float ax = verts[3 * i0], ay = verts[3 * i0 + 1], az = verts[3 * i0 + 2];
        float bx = verts[3 * i1], by = verts[3 * i1 + 1], bz = verts[3 * i1 + 2];
        float qx = verts[3 * i2], qy = verts[3 * i2 + 1], qz = verts[3 * i2 + 2];
        float ux = ax - bx, uy = ay - by, uz = az - bz;
        float vx = qx - bx, vy = qy - by, vz = qz - bz;
        nx = 0.5f * (uy * vz - uz * vy);
        ny = 0.5f * (uz * vx - ux * vz);
        nz = 0.5f * (ux * vy - uy * vx);
        cx = (ax + bx + qx) * (1.0f / 3.0f);
        cy = (ay + by + qy) * (1.0f / 3.0f);
        cz = (az + bz + qz) * (1.0f / 3.0f);
    } else {
        int t = p - N;
        cx = tcent[3 * t]; cy = tcent[3 * t + 1]; cz = tcent[3 * t + 2];
        nx = -tnorm[3 * t]; ny = -tnorm[3 * t + 1]; nz = -tnorm[3 * t + 2];
    }

    unsigned short chx = f2bf(cx), chy = f2bf(cy), chz = f2bf(cz);
    unsigned short clx = f2bf(cx - bf2f(chx));
    unsigned short cly = f2bf(cy - bf2f(chy));
    unsigned short clz = f2bf(cz - bf2f(chz));
    unsigned short nhx = f2bf(nx), nhy = f2bf(ny), nhz = f2bf(nz);
    unsigned short nlx = f2bf(nx - bf2f(nhx));
    unsigned short nly = f2bf(ny - bf2f(nhy));
    unsigned short nlz = f2bf(nz - bf2f(nhz));
    float ex = bf2f(chx) + bf2f(clx);
    float ey = bf2f(chy) + bf2f(cly);
    float ez = bf2f(chz) + bf2f(clz);
    float s = ex * ex + ey * ey + ez * ez;
    unsigned short sh = f2bf(s), sl = f2bf(s - bf2f(sh));
    unsigned short m2hx = f2bf(-2.0f * bf2f(chx)), m2hy = f2bf(-2.0f * bf2f(chy)), m2hz = f2bf(-2.0f * bf2f(chz));
    unsigned short m2lx = f2bf(-2.0f * bf2f(clx)), m2ly = f2bf(-2.0f * bf2f(cly)), m2lz = f2bf(-2.0f * bf2f(clz));
    const unsigned short one = 0x3F80;

    __align__(16) unsigned short A1v[16] = {
        m2hx, m2hy, m2hz,  m2hx, m2hy, m2hz,  m2lx, m2ly, m2lz,
        sh, sl,  one, one,  one,  0, 0 };
    __align__(16) unsigned short B1v[16] = {
        chx, chy, chz,  clx, cly, clz,  chx, chy, chz,
        one, one,  sh, sl,  one,  0, 0 };
    __align__(16) unsigned short A2v[16] = {
        nhx, nhy, nhz,  nhx, nhy, nhz,  nlx, nly, nlz,
        0, 0, 0, 0, 0, 0, 0 };
    __align__(16) unsigned short B2v[16] = {
        nhx, nhy, nhz,  nlx, nly, nlz,  nhx, nhy, nhz,
        0, 0, 0, 0, 0, 0, 0 };

    size_t arr = (size_t)P * 16;
    unsigned short* A1 = ws;
    unsigned short* A2 = ws + arr;
    unsigned short* B1 = ws + 2 * arr;
    unsigned short* B2 = ws + 3 * arr;

    int tile = p >> 5, m = p & 31;
    size_t lo = ((size_t)tile * 64 + m) * 8;       // k0..7 -> lane m
    size_t hi = lo + 32 * 8;                       // k8..15 -> lane 32+m

    *(uint4*)(A1 + lo) = *(const uint4*)&A1v[0];
    *(uint4*)(A1 + hi) = *(const uint4*)&A1v[8];
    *(uint4*)(A2 + lo) = *(const uint4*)&A2v[0];
    *(uint4*)(A2 + hi) = *(const uint4*)&A2v[8];
    *(uint4*)(B1 + lo) = *(const uint4*)&B1v[0];
    *(uint4*)(B1 + hi) = *(const uint4*)&B1v[8];
    *(uint4*)(B2 + lo) = *(const uint4*)&B2v[0];
    *(uint4*)(B2 + hi) = *(const uint4*)&B2v[8];
}

// 4-way batched reciprocal: sum of 4 x/a terms via 1 rcp (trans-pipe 4x cut).
static __device__ __forceinline__ void acc4(float4& part, const f32x16& d1, const f32x16& d2) {
#pragma unroll
    for (int g = 0; g < 4; ++g) {
        const int r = 4 * g;
        float p01 = d1[r] * d1[r + 1];
        float p23 = d1[r + 2] * d1[r + 3];
        float n01 = fmaf(d2[r], d1[r + 1], d2[r + 1] * d1[r]);
        float n23 = fmaf(d2[r + 2], d1[r + 3], d2[r + 3] * d1[r + 2]);
        float t   = p01 * p23;
        float num = fmaf(n01, p23, n23 * p01);
        (&part.x)[g] = fmaf(num, __builtin_amdgcn_rcpf(t), (&part.x)[g]);
    }
}

// Kernel 2: row-paired circular sweep -- stage-once LDS blocks.
// Rows (I0=2rp, I1=I0+1) share j-window W=[I0+1, I0+256] (mod nT):
//   contrib(rp) = 2*sum_W [T(I0,j)+T(I1,j)]
//               + T(I0,I0) + T(I1,I0+257) - T(I0,I0+256) - T(I1,I0+1)
// Block = (rp, c in 0..15): stages slots s=0..17 (offsets d=16c+s) into LDS
// via global_load_lds, ONE __syncthreads (nothing in flight to lose -- the
// R12 trap was re-staging across barriers), then the hot loop is LDS-only:
// wave wv consumes slots 1+4wv..4+4wv. Corrections: slots 0/1 (c=0, wave 0)
// and 16/17 (c=15, wave 3). 4096 small blocks, 4 blocks/CU (36.9 KB LDS):
// concurrent blocks in different phases provide the stage/compute overlap
// intra-wave prefetch never achieved. NO explicit s_waitcnt (R14 pathology).
__global__ __launch_bounds__(256, 4) void dc_pair_mfma(
    const unsigned short* __restrict__ ws, float* __restrict__ out, int P) {
    __shared__ unsigned short sB[18][1024];   // slot = [b1(512) | b2(512)] shorts
    __shared__ float wsum[4];

    const int nT = P >> 5;                     // 512
    size_t arr = (size_t)P * 16;
    const unsigned short* A1 = ws;
    const unsigned short* A2 = ws + arr;
    const unsigned short* B1 = ws + 2 * arr;
    const unsigned short* B2 = ws + 3 * arr;

    int tid = threadIdx.x;
    int lane = tid & 63, wv = tid >> 6;
    int bx = blockIdx.x;                       // 0..4095
    int rp = bx >> 4, c = bx & 15;
    int I0 = 2 * rp, I1 = I0 + 1;

    const size_t lo = (size_t)lane * 8;        // shorts: lane's 16B frag chunk

    // ---- stage 18 slots (wave wv: s = wv, wv+4, ...), async fire-and-forget
    for (int s = wv; s < 18; s += 4) {
        int j = I0 + 16 * c + s;               // raw max 510+240+17 = 767
        if (j >= nT) j -= nT;
        GLOAD_LDS16(B1 + (size_t)j * 512 + lo, &sB[s][0]);
        GLOAD_LDS16(B2 + (size_t)j * 512 + lo, &sB[s][512]);
    }

    // A fragments (register loads, compiler-managed waits)
    bf16x8 a1_0 = *(const bf16x8*)(A1 + (size_t)I0 * 512 + lo);
    bf16x8 a2_0 = *(const bf16x8*)(A2 + (size_t)I0 * 512 + lo);
    bf16x8 a1_1 = *(const bf16x8*)(A1 + (size_t)I1 * 512 + lo);
    bf16x8 a2_1 = *(const bf16x8*)(A2 + (size_t)I1 * 512 + lo);

    __syncthreads();                           // staging complete; LDS-only below

    const f32x16 zero = {0.f,0.f,0.f,0.f,0.f,0.f,0.f,0.f,0.f,0.f,0.f,0.f,0.f,0.f,0.f,0.f};
    float4 partA = make_float4(0.f, 0.f, 0.f, 0.f);

    // ---- hot loop: 4 tiles per wave, zero global loads, zero barriers
#pragma unroll
    for (int t = 0; t < 4; ++t) {
        int s = 1 + 4 * wv + t;
        const bf16x8 b1 = *(const bf16x8*)&sB[s][lane * 8];
        const bf16x8 b2 = *(const bf16x8*)&sB[s][512 + lane * 8];
        f32x16 d1 = __builtin_amdgcn_mfma_f32_32x32x16_bf16(a1_0, b1, zero, 0, 0, 0);
        f32x16 d2 = __builtin_amdgcn_mfma_f32_32x32x16_bf16(a2_0, b2, zero, 0, 0, 0);
        acc4(partA, d1, d2);
        f32x16 e1 = __builtin_amdgcn_mfma_f32_32x32x16_bf16(a1_1, b1, zero, 0, 0, 0);
        f32x16 e2 = __builtin_amdgcn_mfma_f32_32x32x16_bf16(a2_1, b2, zero, 0, 0, 0);
        acc4(partA, e1, e2);
    }

    float sacc = 2.0f * (partA.x + partA.y + partA.z + partA.w);

    // ---- corrections from staged slots (exact R10 algebra)
    auto corr_tile = [&](const bf16x8& x1, const bf16x8& x2, int s) -> float {
        const bf16x8 b1 = *(const bf16x8*)&sB[s][lane * 8];
        const bf16x8 b2 = *(const bf16x8*)&sB[s][512 + lane * 8];
        f32x16 d1 = __builtin_amdgcn_mfma_f32_32x32x16_bf16(x1, b1, zero, 0, 0, 0);
        f32x16 d2 = __builtin_amdgcn_mfma_f32_32x32x16_bf16(x2, b2, zero, 0, 0, 0);
        float4 p = make_float4(0.f, 0.f, 0.f, 0.f);
        acc4(p, d1, d2);
        return p.x + p.y + p.z + p.w;
    };
    if (c == 0 && wv == 0) {
        sacc += corr_tile(a1_0, a2_0, 0);      // +T(I0,I0)       (d=0)
        sacc -= corr_tile(a1_1, a2_1, 1);      // -T(I1,I0+1)     (d=1)
    } else if (c == 15 && wv == 3) {
        sacc -= corr_tile(a1_0, a2_0, 16);     // -T(I0,I0+256)   (d=256)
        sacc += corr_tile(a1_1, a2_1, 17);     // +T(I1,I0+257)   (d=257)
    }

#pragma unroll
    for (int off = 32; off > 0; off >>= 1) sacc += __shfl_down(sacc, off, 64);
    if (lane == 0) wsum[wv] = sacc;
    __syncthreads();
    if (tid == 0) {
        float t = wsum[0] + wsum[1] + wsum[2] + wsum[3];
        atomicAdd(out, t);
    }
}

extern "C" void kernel_launch(void* const* d_in, const int* in_sizes, int n_in,
                              void* d_out, int out_size, void* d_ws, size_t ws_size,
                              hipStream_t stream) {
    const float* verts = (const float*)d_in[0];   // (V,3) f32
    const float* tnorm = (const float*)d_in[1];   // (M,3) f32
    const float* tcent = (const float*)d_in[2];   // (M,3) f32
    const int*   sidx  = (const int*)d_in[3];     // (N,3) i32

    int M = in_sizes[1] / 3;
    int N = in_sizes[3] / 3;
    int P = N + M;                                // 16384

    unsigned short* ws = (unsigned short*)d_ws;   // A1|A2|B1|B2 = 4 MB
    float* out = (float*)d_out;

    int bblocks = (P + 255) / 256;
    dc_pack<<<bblocks, 256, 0, stream>>>(verts, tnorm, tcent, sidx, ws, out, N, M);

    // 256 rp x 16 chunks = 4096 blocks (4/CU granted, 4 uniform batches)
    dc_pair_mfma<<<4096, 256, 0, stream>>>(ws, out, P);
}